// Round 1
// baseline (394.500 us; speedup 1.0000x reference)
//
#include <hip/hip_runtime.h>

typedef unsigned int u32;
typedef unsigned short u16;
typedef __bf16 bf16x8 __attribute__((ext_vector_type(8)));
typedef float f32x4 __attribute__((ext_vector_type(4)));

#define HID 128

__device__ __forceinline__ u16 f2bf(float f) {
  u32 u = __float_as_uint(f);
  u32 r = u + 0x7FFFu + ((u >> 16) & 1u);
  return (u16)(r >> 16);
}

// ---- CSR build ----------------------------------------------------------
__global__ void k_deg(const int* __restrict__ dst, int* __restrict__ deg, int E) {
  int e = blockIdx.x * blockDim.x + threadIdx.x;
  if (e < E) atomicAdd(&deg[dst[e]], 1);
}

__global__ void k_scan(const int* __restrict__ deg, int* __restrict__ row_ptr, int n) {
  __shared__ int sm[1024];
  __shared__ int carry_s;
  int tid = threadIdx.x;
  if (tid == 0) { carry_s = 0; row_ptr[0] = 0; }
  __syncthreads();
  for (int base = 0; base < n; base += 1024) {
    int i = base + tid;
    int v = (i < n) ? deg[i] : 0;
    sm[tid] = v;
    __syncthreads();
    for (int off = 1; off < 1024; off <<= 1) {
      int t = (tid >= off) ? sm[tid - off] : 0;
      __syncthreads();
      sm[tid] += t;
      __syncthreads();
    }
    if (i < n) row_ptr[i + 1] = carry_s + sm[tid];
    __syncthreads();
    if (tid == 0) carry_s += sm[1023];
    __syncthreads();
  }
}

__global__ void k_scatter(const int* __restrict__ src, const int* __restrict__ dst,
                          const int* __restrict__ row_ptr, int* __restrict__ cursor,
                          int* __restrict__ col, int E) {
  int e = blockIdx.x * blockDim.x + threadIdx.x;
  if (e < E) {
    int d = dst[e];
    int p = atomicAdd(&cursor[d], 1);
    col[row_ptr[d] + p] = src[e];
  }
}

// ---- fp32 -> bf16 feature convert (2 elems/thread) ----------------------
__global__ void k_cvt(const float* __restrict__ x, u16* __restrict__ xb, int n2) {
  int i = blockIdx.x * blockDim.x + threadIdx.x;
  if (i < n2) {
    float f0 = x[2 * i], f1 = x[2 * i + 1];
    ((u32*)xb)[i] = (u32)f2bf(f0) | ((u32)f2bf(f1) << 16);
  }
}

// ---- pack W [128 x N] fp32 -> MFMA B-fragment order bf16 ----------------
// P[nt][kt][lane][j] = W[(kt*32 + (lane>>4)*8 + j)*N + nt*16 + (lane&15)]
__global__ void k_pack(const float* __restrict__ W, u16* __restrict__ P, int N) {
  int t = blockIdx.x * blockDim.x + threadIdx.x;
  int total = (N / 16) * 4 * 64;
  if (t >= total) return;
  int lane = t & 63;
  int kt = (t >> 6) & 3;
  int nt = t >> 8;
  int colc = nt * 16 + (lane & 15);
  int krow = kt * 32 + (lane >> 4) * 8;
  u16* d = P + (size_t)t * 8;
#pragma unroll
  for (int j = 0; j < 8; ++j) d[j] = f2bf(W[(krow + j) * N + colc]);
}

// ---- mean aggregation: one wave per node, 2 dims/lane -------------------
__global__ void k_agg(const u16* __restrict__ feat, const int* __restrict__ row_ptr,
                      const int* __restrict__ col, u16* __restrict__ agg, int n) {
  int w = (blockIdx.x * blockDim.x + threadIdx.x) >> 6;
  int lane = threadIdx.x & 63;
  if (w >= n) return;
  int beg = row_ptr[w], end = row_ptr[w + 1];
  float a0 = 0.f, a1 = 0.f;
#pragma unroll 2
  for (int e = beg; e < end; ++e) {
    int j = col[e];
    u32 u = *(const u32*)(feat + (size_t)j * HID + lane * 2);
    a0 += __uint_as_float(u << 16);
    a1 += __uint_as_float(u & 0xFFFF0000u);
  }
  int d = end - beg;
  if (d < 1) d = 1;
  float inv = 1.0f / (float)d;
  a0 *= inv;
  a1 *= inv;
  u32 o = (u32)f2bf(a0) | ((u32)f2bf(a1) << 16);
  *(u32*)(agg + (size_t)w * HID + lane * 2) = o;
}

// ---- fused GEMM: out = agg@Wl + h@Wr + b (+relu), MFMA 16x16x32 bf16 ----
// one wave per 16-row tile, NT 16-col tiles (N = NT*16)
template <int NT, bool RELU, bool OUTF32>
__global__ void k_gemm(const u16* __restrict__ Aagg, const u16* __restrict__ Ah,
                       const u16* __restrict__ Pl, const u16* __restrict__ Pr,
                       const float* __restrict__ bias, void* __restrict__ outp,
                       int mtiles) {
  int w = (blockIdx.x * blockDim.x + threadIdx.x) >> 6;
  if (w >= mtiles) return;
  int lane = threadIdx.x & 63;

  f32x4 acc[NT];
#pragma unroll
  for (int nt = 0; nt < NT; ++nt) acc[nt] = 0.f;

  int row = w * 16 + (lane & 15);
  int kg = lane >> 4;
  const u16* abase_a = Aagg + (size_t)row * HID + kg * 8;
  const u16* abase_h = Ah + (size_t)row * HID + kg * 8;

#pragma unroll
  for (int kt = 0; kt < 4; ++kt) {
    bf16x8 af = *(const bf16x8*)(abase_a + kt * 32);
#pragma unroll
    for (int nt = 0; nt < NT; ++nt) {
      bf16x8 bf = *(const bf16x8*)(Pl + ((size_t)(nt * 4 + kt) * 64 + lane) * 8);
      acc[nt] = __builtin_amdgcn_mfma_f32_16x16x32_bf16(af, bf, acc[nt], 0, 0, 0);
    }
  }
#pragma unroll
  for (int kt = 0; kt < 4; ++kt) {
    bf16x8 af = *(const bf16x8*)(abase_h + kt * 32);
#pragma unroll
    for (int nt = 0; nt < NT; ++nt) {
      bf16x8 bf = *(const bf16x8*)(Pr + ((size_t)(nt * 4 + kt) * 64 + lane) * 8);
      acc[nt] = __builtin_amdgcn_mfma_f32_16x16x32_bf16(af, bf, acc[nt], 0, 0, 0);
    }
  }

  const int N = NT * 16;
  int col0 = lane & 15;
  int rq = lane >> 4;
#pragma unroll
  for (int nt = 0; nt < NT; ++nt) {
    float bv = bias[nt * 16 + col0];
#pragma unroll
    for (int j = 0; j < 4; ++j) {
      float v = acc[nt][j] + bv;
      if (RELU) v = fmaxf(v, 0.f);
      int r = w * 16 + rq * 4 + j;
      if (OUTF32)
        ((float*)outp)[(size_t)r * N + nt * 16 + col0] = v;
      else
        ((u16*)outp)[(size_t)r * N + nt * 16 + col0] = f2bf(v);
    }
  }
}

extern "C" void kernel_launch(void* const* d_in, const int* in_sizes, int n_in,
                              void* d_out, int out_size, void* d_ws, size_t ws_size,
                              hipStream_t stream) {
  const float* x = (const float*)d_in[0];
  const int* ei = (const int*)d_in[1];
  const float* W1l = (const float*)d_in[2];
  const float* W1r = (const float*)d_in[3];
  const float* b1 = (const float*)d_in[4];
  const float* W2l = (const float*)d_in[5];
  const float* W2r = (const float*)d_in[6];
  const float* b2 = (const float*)d_in[7];
  const float* W3l = (const float*)d_in[8];
  const float* W3r = (const float*)d_in[9];
  const float* b3 = (const float*)d_in[10];

  const int E = in_sizes[1] / 2;
  const int N = in_sizes[0] / HID;
  const int* esrc = ei;
  const int* edst = ei + E;

  char* wp = (char*)d_ws;
  auto alloc = [&](size_t b) {
    char* p = wp;
    wp += (b + 255) & ~(size_t)255;
    return p;
  };
  int* deg = (int*)alloc((size_t)N * 4);
  int* rp = (int*)alloc((size_t)(N + 1) * 4);
  int* cur = (int*)alloc((size_t)N * 4);
  int* col = (int*)alloc((size_t)E * 4);
  u16* featA = (u16*)alloc((size_t)N * HID * 2);
  u16* featB = (u16*)alloc((size_t)N * HID * 2);
  u16* aggb = (u16*)alloc((size_t)N * HID * 2);
  u16* P1l = (u16*)alloc(8 * 4 * 64 * 8 * 2);
  u16* P1r = (u16*)alloc(8 * 4 * 64 * 8 * 2);
  u16* P2l = (u16*)alloc(8 * 4 * 64 * 8 * 2);
  u16* P2r = (u16*)alloc(8 * 4 * 64 * 8 * 2);
  u16* P3l = (u16*)alloc(4 * 4 * 64 * 8 * 2);
  u16* P3r = (u16*)alloc(4 * 4 * 64 * 8 * 2);

  hipMemsetAsync(deg, 0, (size_t)N * 4, stream);
  hipMemsetAsync(cur, 0, (size_t)N * 4, stream);

  int eb = (E + 255) / 256;
  k_deg<<<eb, 256, 0, stream>>>(edst, deg, E);
  k_scan<<<1, 1024, 0, stream>>>(deg, rp, N);
  k_scatter<<<eb, 256, 0, stream>>>(esrc, edst, rp, cur, col, E);

  int n2 = N * (HID / 2);
  k_cvt<<<(n2 + 255) / 256, 256, 0, stream>>>(x, featA, n2);

  k_pack<<<(2048 + 255) / 256, 256, 0, stream>>>(W1l, P1l, 128);
  k_pack<<<(2048 + 255) / 256, 256, 0, stream>>>(W1r, P1r, 128);
  k_pack<<<(2048 + 255) / 256, 256, 0, stream>>>(W2l, P2l, 128);
  k_pack<<<(2048 + 255) / 256, 256, 0, stream>>>(W2r, P2r, 128);
  k_pack<<<(1024 + 255) / 256, 256, 0, stream>>>(W3l, P3l, 64);
  k_pack<<<(1024 + 255) / 256, 256, 0, stream>>>(W3r, P3r, 64);

  int ab = (N * 64 + 255) / 256;           // one wave per node
  int mtiles = N / 16;
  int gb = (mtiles * 64 + 255) / 256;      // one wave per 16-row tile

  // layer 1: in featA(x) -> out featB
  k_agg<<<ab, 256, 0, stream>>>(featA, rp, col, aggb, N);
  k_gemm<8, true, false><<<gb, 256, 0, stream>>>(aggb, featA, P1l, P1r, b1, featB, mtiles);
  // layer 2: in featB -> out featA
  k_agg<<<ab, 256, 0, stream>>>(featB, rp, col, aggb, N);
  k_gemm<8, true, false><<<gb, 256, 0, stream>>>(aggb, featB, P2l, P2r, b2, featA, mtiles);
  // layer 3: in featA -> out d_out (fp32, no relu)
  k_agg<<<ab, 256, 0, stream>>>(featA, rp, col, aggb, N);
  k_gemm<4, false, true><<<gb, 256, 0, stream>>>(aggb, featA, P3l, P3r, b3, (float*)d_out, mtiles);
}

// Round 3
// 314.471 us; speedup vs baseline: 1.2545x; 1.2545x over previous
//
#include <hip/hip_runtime.h>

typedef unsigned int u32;
typedef unsigned short u16;
typedef __bf16 bf16x8 __attribute__((ext_vector_type(8)));
typedef float f32x4 __attribute__((ext_vector_type(4)));

#define HID 128

__device__ __forceinline__ u16 f2bf(float f) {
  u32 u = __float_as_uint(f);
  u32 r = u + 0x7FFFu + ((u >> 16) & 1u);
  return (u16)(r >> 16);
}

// ---- CSR build ----------------------------------------------------------
__global__ void k_deg(const int* __restrict__ dst, int* __restrict__ deg, int E) {
  int e = blockIdx.x * blockDim.x + threadIdx.x;
  if (e < E) atomicAdd(&deg[dst[e]], 1);
}

// per-block inclusive scan of 1024-chunks; row_ptr[i+1] = partial, bsum[b] = chunk total
__global__ void k_blockscan(const int* __restrict__ deg, int* __restrict__ row_ptr,
                            int* __restrict__ bsum, int n) {
  __shared__ int sm[1024];
  int tid = threadIdx.x;
  int i = blockIdx.x * 1024 + tid;
  int v = (i < n) ? deg[i] : 0;
  sm[tid] = v;
  __syncthreads();
  for (int off = 1; off < 1024; off <<= 1) {
    int t = (tid >= off) ? sm[tid - off] : 0;
    __syncthreads();
    sm[tid] += t;
    __syncthreads();
  }
  if (i < n) row_ptr[i + 1] = sm[tid];
  if (tid == 1023) bsum[blockIdx.x] = sm[1023];
  if (i == 0) row_ptr[0] = 0;
}

// single-wave exclusive scan of block sums (nb <= 64)
__global__ void k_bsum_scan(int* __restrict__ bsum, int nb) {
  int tid = threadIdx.x;
  int orig = (tid < nb) ? bsum[tid] : 0;
  int v = orig;
  for (int off = 1; off < 64; off <<= 1) {
    int t = __shfl_up(v, off);
    if (tid >= off) v += t;
  }
  if (tid < nb) bsum[tid] = v - orig;  // exclusive
}

__global__ void k_addoff(int* __restrict__ row_ptr, const int* __restrict__ bsum, int n) {
  int i = blockIdx.x * blockDim.x + threadIdx.x;  // covers row_ptr[1..n]
  if (i < n) row_ptr[i + 1] += bsum[i >> 10];
}

__global__ void k_scatter(const int* __restrict__ src, const int* __restrict__ dst,
                          const int* __restrict__ row_ptr, int* __restrict__ cursor,
                          int* __restrict__ col, int E) {
  int e = blockIdx.x * blockDim.x + threadIdx.x;
  if (e < E) {
    int d = dst[e];
    int p = atomicAdd(&cursor[d], 1);
    col[row_ptr[d] + p] = src[e];
  }
}

// ---- fp32 -> bf16 feature convert (2 elems/thread) ----------------------
__global__ void k_cvt(const float* __restrict__ x, u16* __restrict__ xb, int n2) {
  int i = blockIdx.x * blockDim.x + threadIdx.x;
  if (i < n2) {
    float f0 = x[2 * i], f1 = x[2 * i + 1];
    ((u32*)xb)[i] = (u32)f2bf(f0) | ((u32)f2bf(f1) << 16);
  }
}

// ---- pack W [128 x N] fp32 -> MFMA B-fragment order bf16 ----------------
// P[nt][kt][lane][j] = W[(kt*32 + (lane>>4)*8 + j)*N + nt*16 + (lane&15)]
__global__ void k_pack(const float* __restrict__ W, u16* __restrict__ P, int N) {
  int t = blockIdx.x * blockDim.x + threadIdx.x;
  int total = (N / 16) * 4 * 64;
  if (t >= total) return;
  int lane = t & 63;
  int kt = (t >> 6) & 3;
  int nt = t >> 8;
  int colc = nt * 16 + (lane & 15);
  int krow = kt * 32 + (lane >> 4) * 8;
  u16* d = P + (size_t)t * 8;
#pragma unroll
  for (int j = 0; j < 8; ++j) d[j] = f2bf(W[(krow + j) * N + colc]);
}

// ---- mean aggregation: one wave per node, 2 dims/lane -------------------
__global__ void k_agg(const u16* __restrict__ feat, const int* __restrict__ row_ptr,
                      const int* __restrict__ col, u16* __restrict__ agg, int n) {
  int w = (blockIdx.x * blockDim.x + threadIdx.x) >> 6;
  int lane = threadIdx.x & 63;
  if (w >= n) return;
  int beg = row_ptr[w], end = row_ptr[w + 1];
  float a0 = 0.f, a1 = 0.f;
#pragma unroll 2
  for (int e = beg; e < end; ++e) {
    int j = col[e];
    u32 u = *(const u32*)(feat + (size_t)j * HID + lane * 2);
    a0 += __uint_as_float(u << 16);
    a1 += __uint_as_float(u & 0xFFFF0000u);
  }
  int d = end - beg;
  if (d < 1) d = 1;
  float inv = 1.0f / (float)d;
  a0 *= inv;
  a1 *= inv;
  u32 o = (u32)f2bf(a0) | ((u32)f2bf(a1) << 16);
  *(u32*)(agg + (size_t)w * HID + lane * 2) = o;
}

// ---- fused GEMM: out = agg@Wl + h@Wr + b (+relu), MFMA 16x16x32 bf16 ----
// one wave per 16-row tile, NT 16-col tiles (N = NT*16)
template <int NT, bool RELU, bool OUTF32>
__global__ void k_gemm(const u16* __restrict__ Aagg, const u16* __restrict__ Ah,
                       const u16* __restrict__ Pl, const u16* __restrict__ Pr,
                       const float* __restrict__ bias, void* __restrict__ outp,
                       int mtiles) {
  int w = (blockIdx.x * blockDim.x + threadIdx.x) >> 6;
  if (w >= mtiles) return;
  int lane = threadIdx.x & 63;

  f32x4 acc[NT];
#pragma unroll
  for (int nt = 0; nt < NT; ++nt) acc[nt] = 0.f;

  int row = w * 16 + (lane & 15);
  int kg = lane >> 4;
  const u16* abase_a = Aagg + (size_t)row * HID + kg * 8;
  const u16* abase_h = Ah + (size_t)row * HID + kg * 8;

#pragma unroll
  for (int kt = 0; kt < 4; ++kt) {
    bf16x8 af = *(const bf16x8*)(abase_a + kt * 32);
#pragma unroll
    for (int nt = 0; nt < NT; ++nt) {
      bf16x8 bf = *(const bf16x8*)(Pl + ((size_t)(nt * 4 + kt) * 64 + lane) * 8);
      acc[nt] = __builtin_amdgcn_mfma_f32_16x16x32_bf16(af, bf, acc[nt], 0, 0, 0);
    }
  }
#pragma unroll
  for (int kt = 0; kt < 4; ++kt) {
    bf16x8 af = *(const bf16x8*)(abase_h + kt * 32);
#pragma unroll
    for (int nt = 0; nt < NT; ++nt) {
      bf16x8 bf = *(const bf16x8*)(Pr + ((size_t)(nt * 4 + kt) * 64 + lane) * 8);
      acc[nt] = __builtin_amdgcn_mfma_f32_16x16x32_bf16(af, bf, acc[nt], 0, 0, 0);
    }
  }

  const int N = NT * 16;
  int col0 = lane & 15;
  int rq = lane >> 4;
#pragma unroll
  for (int nt = 0; nt < NT; ++nt) {
    float bv = bias[nt * 16 + col0];
#pragma unroll
    for (int j = 0; j < 4; ++j) {
      float v = acc[nt][j] + bv;
      if (RELU) v = fmaxf(v, 0.f);
      int r = w * 16 + rq * 4 + j;
      if (OUTF32)
        ((float*)outp)[(size_t)r * N + nt * 16 + col0] = v;
      else
        ((u16*)outp)[(size_t)r * N + nt * 16 + col0] = f2bf(v);
    }
  }
}

extern "C" void kernel_launch(void* const* d_in, const int* in_sizes, int n_in,
                              void* d_out, int out_size, void* d_ws, size_t ws_size,
                              hipStream_t stream) {
  const float* x = (const float*)d_in[0];
  const int* ei = (const int*)d_in[1];
  const float* W1l = (const float*)d_in[2];
  const float* W1r = (const float*)d_in[3];
  const float* b1 = (const float*)d_in[4];
  const float* W2l = (const float*)d_in[5];
  const float* W2r = (const float*)d_in[6];
  const float* b2 = (const float*)d_in[7];
  const float* W3l = (const float*)d_in[8];
  const float* W3r = (const float*)d_in[9];
  const float* b3 = (const float*)d_in[10];

  const int E = in_sizes[1] / 2;
  const int N = in_sizes[0] / HID;
  const int* esrc = ei;
  const int* edst = ei + E;

  char* wp = (char*)d_ws;
  auto alloc = [&](size_t b) {
    char* p = wp;
    wp += (b + 255) & ~(size_t)255;
    return p;
  };
  int* deg = (int*)alloc((size_t)N * 4);
  int* rp = (int*)alloc((size_t)(N + 1) * 4);
  int* cur = (int*)alloc((size_t)N * 4);
  int* col = (int*)alloc((size_t)E * 4);
  int* bsum = (int*)alloc(64 * 4);
  u16* featA = (u16*)alloc((size_t)N * HID * 2);
  u16* featB = (u16*)alloc((size_t)N * HID * 2);
  u16* aggb = (u16*)alloc((size_t)N * HID * 2);
  u16* P1l = (u16*)alloc(8 * 4 * 64 * 8 * 2);
  u16* P1r = (u16*)alloc(8 * 4 * 64 * 8 * 2);
  u16* P2l = (u16*)alloc(8 * 4 * 64 * 8 * 2);
  u16* P2r = (u16*)alloc(8 * 4 * 64 * 8 * 2);
  u16* P3l = (u16*)alloc(4 * 4 * 64 * 8 * 2);
  u16* P3r = (u16*)alloc(4 * 4 * 64 * 8 * 2);

  hipMemsetAsync(deg, 0, (size_t)N * 4, stream);
  hipMemsetAsync(cur, 0, (size_t)N * 4, stream);

  int eb = (E + 255) / 256;
  int nb = (N + 1023) / 1024;
  k_deg<<<eb, 256, 0, stream>>>(edst, deg, E);
  k_blockscan<<<nb, 1024, 0, stream>>>(deg, rp, bsum, N);
  k_bsum_scan<<<1, 64, 0, stream>>>(bsum, nb);
  k_addoff<<<(N + 255) / 256, 256, 0, stream>>>(rp, bsum, N);
  k_scatter<<<eb, 256, 0, stream>>>(esrc, edst, rp, cur, col, E);

  int n2 = N * (HID / 2);
  k_cvt<<<(n2 + 255) / 256, 256, 0, stream>>>(x, featA, n2);

  k_pack<<<(2048 + 255) / 256, 256, 0, stream>>>(W1l, P1l, 128);
  k_pack<<<(2048 + 255) / 256, 256, 0, stream>>>(W1r, P1r, 128);
  k_pack<<<(2048 + 255) / 256, 256, 0, stream>>>(W2l, P2l, 128);
  k_pack<<<(2048 + 255) / 256, 256, 0, stream>>>(W2r, P2r, 128);
  k_pack<<<(1024 + 255) / 256, 256, 0, stream>>>(W3l, P3l, 64);
  k_pack<<<(1024 + 255) / 256, 256, 0, stream>>>(W3r, P3r, 64);

  int ab = (N * 64 + 255) / 256;           // one wave per node
  int mtiles = N / 16;
  int gb = (mtiles * 64 + 255) / 256;      // one wave per 16-row tile

  // layer 1: in featA(x) -> out featB
  k_agg<<<ab, 256, 0, stream>>>(featA, rp, col, aggb, N);
  k_gemm<8, true, false><<<gb, 256, 0, stream>>>(aggb, featA, P1l, P1r, b1, featB, mtiles);
  // layer 2: in featB -> out featA
  k_agg<<<ab, 256, 0, stream>>>(featB, rp, col, aggb, N);
  k_gemm<8, true, false><<<gb, 256, 0, stream>>>(aggb, featB, P2l, P2r, b2, featA, mtiles);
  // layer 3: in featA -> out d_out (fp32, no relu)
  k_agg<<<ab, 256, 0, stream>>>(featA, rp, col, aggb, N);
  k_gemm<4, false, true><<<gb, 256, 0, stream>>>(aggb, featA, P3l, P3r, b3, (float*)d_out, mtiles);
}

// Round 4
// 273.543 us; speedup vs baseline: 1.4422x; 1.1496x over previous
//
#include <hip/hip_runtime.h>

typedef unsigned int u32;
typedef unsigned short u16;
typedef __bf16 bf16x8 __attribute__((ext_vector_type(8)));
typedef float f32x4 __attribute__((ext_vector_type(4)));

#define HID 128

__device__ __forceinline__ u16 f2bf(float f) {
  u32 u = __float_as_uint(f);
  u32 r = u + 0x7FFFu + ((u >> 16) & 1u);
  return (u16)(r >> 16);
}
__device__ __forceinline__ float bflo(u32 a) { return __uint_as_float(a << 16); }
__device__ __forceinline__ float bfhi(u32 a) { return __uint_as_float(a & 0xFFFF0000u); }

// ---- CSR build ----------------------------------------------------------
// deg[d]++ and remember this edge's rank within its destination segment.
__global__ void k_deg(const int* __restrict__ dst, int* __restrict__ deg,
                      int* __restrict__ rank, int E) {
  int e = blockIdx.x * blockDim.x + threadIdx.x;
  if (e < E) rank[e] = atomicAdd(&deg[dst[e]], 1);
}

// segment allocator: per-wave prefix sum of deg + one atomic per wave.
// rp[i] = exclusive offset of node i's segment (segments in arbitrary order).
__global__ void k_alloc(const int* __restrict__ deg, int* __restrict__ rp,
                        int* __restrict__ total, int n) {
  int i = blockIdx.x * blockDim.x + threadIdx.x;
  int lane = threadIdx.x & 63;
  int d = (i < n) ? deg[i] : 0;
  int incl = d;
#pragma unroll
  for (int off = 1; off < 64; off <<= 1) {
    int t = __shfl_up(incl, off);
    if (lane >= off) incl += t;
  }
  int wtot = __shfl(incl, 63);
  int base = 0;
  if (lane == 63) base = atomicAdd(total, wtot);
  base = __shfl(base, 63);
  if (i < n) rp[i] = base + incl - d;
}

__global__ void k_scatter(const int* __restrict__ src, const int* __restrict__ dst,
                          const int* __restrict__ rp, const int* __restrict__ rank,
                          int* __restrict__ col, int E) {
  int e = blockIdx.x * blockDim.x + threadIdx.x;
  if (e < E) col[rp[dst[e]] + rank[e]] = src[e];
}

// ---- prep: all weight packs + feature fp32->bf16 convert, one launch ----
// P[nt][kt][lane][j] = W[(kt*32 + (lane>>4)*8 + j)*N + nt*16 + (lane&15)]
__device__ __forceinline__ void pack_one(const float* __restrict__ W,
                                         u16* __restrict__ P, int N, int t) {
  int lane = t & 63;
  int kt = (t >> 6) & 3;
  int nt = t >> 8;
  int colc = nt * 16 + (lane & 15);
  int krow = kt * 32 + (lane >> 4) * 8;
  u16* d = P + (size_t)t * 8;
#pragma unroll
  for (int j = 0; j < 8; ++j) d[j] = f2bf(W[(krow + j) * N + colc]);
}

__global__ void k_prep(const float* __restrict__ x, u32* __restrict__ xb, int n4,
                       const float* __restrict__ W1l, const float* __restrict__ W1r,
                       const float* __restrict__ W2l, const float* __restrict__ W2r,
                       const float* __restrict__ W3l, const float* __restrict__ W3r,
                       u16* __restrict__ P1l, u16* __restrict__ P1r,
                       u16* __restrict__ P2l, u16* __restrict__ P2r,
                       u16* __restrict__ P3l, u16* __restrict__ P3r) {
  int t = blockIdx.x * blockDim.x + threadIdx.x;
  if (t < 10240) {
    if (t < 2048) pack_one(W1l, P1l, 128, t);
    else if (t < 4096) pack_one(W1r, P1r, 128, t - 2048);
    else if (t < 6144) pack_one(W2l, P2l, 128, t - 4096);
    else if (t < 8192) pack_one(W2r, P2r, 128, t - 6144);
    else if (t < 9216) pack_one(W3l, P3l, 64, t - 8192);
    else pack_one(W3r, P3r, 64, t - 9216);
    return;
  }
  int c = t - 10240;
  if (c < n4) {
    f32x4 v = ((const f32x4*)x)[c];
    u32 o0 = (u32)f2bf(v[0]) | ((u32)f2bf(v[1]) << 16);
    u32 o1 = (u32)f2bf(v[2]) | ((u32)f2bf(v[3]) << 16);
    xb[c * 2] = o0;
    xb[c * 2 + 1] = o1;
  }
}

// ---- mean aggregation: one wave per node, 4-edge pipeline ---------------
__global__ void k_agg(const u16* __restrict__ feat, const int* __restrict__ rp,
                      const int* __restrict__ deg, const int* __restrict__ col,
                      u16* __restrict__ agg, int n) {
  int w = (blockIdx.x * blockDim.x + threadIdx.x) >> 6;
  int lane = threadIdx.x & 63;
  if (w >= n) return;
  int beg = rp[w];
  int d = deg[w];
  int end = beg + d;
  const u32* fb = (const u32*)feat + lane;  // row stride 64 u32
  float s0 = 0.f, s1 = 0.f, t0 = 0.f, t1 = 0.f;
  float u0 = 0.f, u1 = 0.f, v0 = 0.f, v1 = 0.f;
  int e = beg;
  for (; e + 4 <= end; e += 4) {
    int j0 = col[e], j1 = col[e + 1], j2 = col[e + 2], j3 = col[e + 3];
    u32 a = fb[(size_t)j0 * 64];
    u32 b = fb[(size_t)j1 * 64];
    u32 c = fb[(size_t)j2 * 64];
    u32 dd = fb[(size_t)j3 * 64];
    s0 += bflo(a); s1 += bfhi(a);
    t0 += bflo(b); t1 += bfhi(b);
    u0 += bflo(c); u1 += bfhi(c);
    v0 += bflo(dd); v1 += bfhi(dd);
  }
  for (; e < end; ++e) {
    int j = col[e];
    u32 a = fb[(size_t)j * 64];
    s0 += bflo(a); s1 += bfhi(a);
  }
  float a0 = (s0 + t0) + (u0 + v0);
  float a1 = (s1 + t1) + (u1 + v1);
  float inv = 1.0f / (float)max(d, 1);
  a0 *= inv;
  a1 *= inv;
  *(u32*)(agg + (size_t)w * HID + lane * 2) = (u32)f2bf(a0) | ((u32)f2bf(a1) << 16);
}

// ---- fused GEMM: out = agg@Wl + h@Wr + b (+relu), MFMA 16x16x32 bf16 ----
// one wave per MR 16-row tiles, NT 16-col tiles (N = NT*16)
template <int NT, int MR, bool RELU, bool OUTF32>
__global__ void k_gemm(const u16* __restrict__ Aagg, const u16* __restrict__ Ah,
                       const u16* __restrict__ Pl, const u16* __restrict__ Pr,
                       const float* __restrict__ bias, void* __restrict__ outp,
                       int mtiles, int n) {
  int wv = (blockIdx.x * blockDim.x + threadIdx.x) >> 6;
  int lane = threadIdx.x & 63;
  int tile0 = wv * MR;
  if (tile0 >= mtiles) return;

  f32x4 acc[MR][NT];
#pragma unroll
  for (int mr = 0; mr < MR; ++mr)
#pragma unroll
    for (int nt = 0; nt < NT; ++nt) acc[mr][nt] = 0.f;

  int rl = lane & 15;
  int kg = lane >> 4;
  int tm[MR];
  const u16 *pa[MR], *ph[MR];
#pragma unroll
  for (int mr = 0; mr < MR; ++mr) {
    tm[mr] = min(tile0 + mr, mtiles - 1);
    int row = tm[mr] * 16 + rl;
    pa[mr] = Aagg + (size_t)row * HID + kg * 8;
    ph[mr] = Ah + (size_t)row * HID + kg * 8;
  }

#pragma unroll
  for (int kt = 0; kt < 4; ++kt) {
    bf16x8 af[MR];
#pragma unroll
    for (int mr = 0; mr < MR; ++mr) af[mr] = *(const bf16x8*)(pa[mr] + kt * 32);
#pragma unroll
    for (int nt = 0; nt < NT; ++nt) {
      bf16x8 bf = *(const bf16x8*)(Pl + ((size_t)(nt * 4 + kt) * 64 + lane) * 8);
#pragma unroll
      for (int mr = 0; mr < MR; ++mr)
        acc[mr][nt] = __builtin_amdgcn_mfma_f32_16x16x32_bf16(af[mr], bf, acc[mr][nt], 0, 0, 0);
    }
  }
#pragma unroll
  for (int kt = 0; kt < 4; ++kt) {
    bf16x8 af[MR];
#pragma unroll
    for (int mr = 0; mr < MR; ++mr) af[mr] = *(const bf16x8*)(ph[mr] + kt * 32);
#pragma unroll
    for (int nt = 0; nt < NT; ++nt) {
      bf16x8 bf = *(const bf16x8*)(Pr + ((size_t)(nt * 4 + kt) * 64 + lane) * 8);
#pragma unroll
      for (int mr = 0; mr < MR; ++mr)
        acc[mr][nt] = __builtin_amdgcn_mfma_f32_16x16x32_bf16(af[mr], bf, acc[mr][nt], 0, 0, 0);
    }
  }

  const int N = NT * 16;
  int rq = lane >> 4;
#pragma unroll
  for (int mr = 0; mr < MR; ++mr) {
#pragma unroll
    for (int nt = 0; nt < NT; ++nt) {
      float bv = bias[nt * 16 + rl];
#pragma unroll
      for (int j = 0; j < 4; ++j) {
        float v = acc[mr][nt][j] + bv;
        if (RELU) v = fmaxf(v, 0.f);
        int r = tm[mr] * 16 + rq * 4 + j;
        if (OUTF32)
          ((float*)outp)[(size_t)r * N + nt * 16 + rl] = v;
        else
          ((u16*)outp)[(size_t)r * N + nt * 16 + rl] = f2bf(v);
      }
    }
  }
}

extern "C" void kernel_launch(void* const* d_in, const int* in_sizes, int n_in,
                              void* d_out, int out_size, void* d_ws, size_t ws_size,
                              hipStream_t stream) {
  const float* x = (const float*)d_in[0];
  const int* ei = (const int*)d_in[1];
  const float* W1l = (const float*)d_in[2];
  const float* W1r = (const float*)d_in[3];
  const float* b1 = (const float*)d_in[4];
  const float* W2l = (const float*)d_in[5];
  const float* W2r = (const float*)d_in[6];
  const float* b2 = (const float*)d_in[7];
  const float* W3l = (const float*)d_in[8];
  const float* W3r = (const float*)d_in[9];
  const float* b3 = (const float*)d_in[10];

  const int E = in_sizes[1] / 2;
  const int N = in_sizes[0] / HID;
  const int* esrc = ei;
  const int* edst = ei + E;

  char* wp = (char*)d_ws;
  auto alloc = [&](size_t b) {
    char* p = wp;
    wp += (b + 255) & ~(size_t)255;
    return p;
  };
  int* deg = (int*)alloc((size_t)(N + 1) * 4);  // deg[N] = total counter
  int* rp = (int*)alloc((size_t)N * 4);
  int* rank = (int*)alloc((size_t)E * 4);
  int* col = (int*)alloc((size_t)E * 4);
  u16* featA = (u16*)alloc((size_t)N * HID * 2);
  u16* featB = (u16*)alloc((size_t)N * HID * 2);
  u16* aggb = (u16*)alloc((size_t)N * HID * 2);
  u16* P1l = (u16*)alloc(8 * 4 * 64 * 8 * 2);
  u16* P1r = (u16*)alloc(8 * 4 * 64 * 8 * 2);
  u16* P2l = (u16*)alloc(8 * 4 * 64 * 8 * 2);
  u16* P2r = (u16*)alloc(8 * 4 * 64 * 8 * 2);
  u16* P3l = (u16*)alloc(4 * 4 * 64 * 8 * 2);
  u16* P3r = (u16*)alloc(4 * 4 * 64 * 8 * 2);

  hipMemsetAsync(deg, 0, (size_t)(N + 1) * 4, stream);

  int eb = (E + 255) / 256;
  k_deg<<<eb, 256, 0, stream>>>(edst, deg, rank, E);
  k_alloc<<<(N + 255) / 256, 256, 0, stream>>>(deg, rp, deg + N, N);
  k_scatter<<<eb, 256, 0, stream>>>(esrc, edst, rp, rank, col, E);

  int n4 = N * (HID / 4);
  k_prep<<<(10240 + n4 + 255) / 256, 256, 0, stream>>>(
      x, (u32*)featA, n4, W1l, W1r, W2l, W2r, W3l, W3r, P1l, P1r, P2l, P2r, P3l, P3r);

  int ab = (N * 64 + 255) / 256;  // one wave per node
  int mtiles = N / 16;            // 3125
  int gwaves = (mtiles + 1) / 2;  // MR=2
  int gb = (gwaves * 64 + 255) / 256;

  // layer 1: featA(x) -> featB
  k_agg<<<ab, 256, 0, stream>>>(featA, rp, deg, col, aggb, N);
  k_gemm<8, 2, true, false><<<gb, 256, 0, stream>>>(aggb, featA, P1l, P1r, b1, featB, mtiles, N);
  // layer 2: featB -> featA
  k_agg<<<ab, 256, 0, stream>>>(featB, rp, deg, col, aggb, N);
  k_gemm<8, 2, true, false><<<gb, 256, 0, stream>>>(aggb, featB, P2l, P2r, b2, featA, mtiles, N);
  // layer 3: featA -> d_out (fp32, no relu)
  k_agg<<<ab, 256, 0, stream>>>(featA, rp, deg, col, aggb, N);
  k_gemm<4, 2, false, true><<<gb, 256, 0, stream>>>(aggb, featA, P3l, P3r, b3, (float*)d_out, mtiles, N);
}